// Round 11
// baseline (231.173 us; speedup 1.0000x reference)
//
#include <hip/hip_runtime.h>
#include <hip/hip_bf16.h>
#include <cstdint>
#include <cstddef>

// B=512, K=32, D=2048, H=512, Z=64; M_all = 16896; M_nn = 16384
#define DEV __device__ __forceinline__

typedef __bf16 bf16;
typedef __bf16 bf16x8 __attribute__((ext_vector_type(8)));
typedef float f32x4 __attribute__((ext_vector_type(4)));

DEV f32x4 mfma16(bf16x8 a, bf16x8 b, f32x4 c) {
  return __builtin_amdgcn_mfma_f32_16x16x32_bf16(a, b, c, 0, 0, 0);
}

DEV void glds16(const void* g, void* l) {
  __builtin_amdgcn_global_load_lds(
      (const __attribute__((address_space(1))) void*)g,
      (__attribute__((address_space(3))) void*)l, 16, 0, 0);
}

// ---------------------------------------------------------------------------
// Stage ROWS x (RB/2 bf16) tile (RB bytes per row, RB = BK*2, pow2) -> LDS.
// XOR swizzle ((row&7)<<4) on the 16B column, applied by pre-swizzling the
// global source column; LDS dest stays linear (glds requirement).
// ---------------------------------------------------------------------------
template<int ROWS, int NT, int RB>
DEV void stage_tile(const bf16* __restrict__ src, int ld, int row0, int k0,
                    unsigned char* lds, int tid) {
  constexpr int CALLS = (ROWS * RB) / (NT * 16);
  const int wid = tid >> 6, lane = tid & 63;
#pragma unroll
  for (int c = 0; c < CALLS; ++c) {
    const int obase = c * (NT * 16) + wid * 1024;   // wave-uniform
    const int o = obase + lane * 16;
    const int row = o / RB;                          // pow2 -> shift
    const int scb = (o & (RB - 1)) ^ ((row & 7) << 4);
    glds16(src + (size_t)(row0 + row) * ld + k0 + (scb >> 1), lds + obase);
  }
}

// ---------------------------------------------------------------------------
// MFMA GEMM: C[M,N] = A[M,K] @ Bt[N,K]^T, bf16 LDS tiles, f32 accum.
// Single-buffered 2-barrier glds loop, K-step = BK.
// R19 model (refit over R0-R10): makespan ~= serial-K-chain x step-cost;
// block ROUNDS pipeline freely (no global barrier), so 2048-block GEMM6
// (4 rounds x 8 steps) runs 40us while 528-block GEMM1 (1 round x 32 steps
// x ~2.8us) runs 90us at the SAME staged bytes. BK=128 regressed (step cost
// scales with bytes when fat): the chain must shrink via SPLIT-K, not BK.
// KCHUNKS>1: blockIdx.z selects a K-window of K/KCHUNKS; MODE 6 writes the
// raw f32 partial to out32 + z*M*N (no atomics; reduce pass sums+bias+relu).
// MODE: 0 relu->bf16; 1 f32+bias; 2 both; 4 mask by hc>0 -> bf16;
//       5 fused loss; 6 raw f32 partial (split-K).
// ---------------------------------------------------------------------------
template<int BM, int BN, int WM, int WN, int MODE, int BK = 64,
         int KCHUNKS = 1, int MINW = 2>
__global__ __launch_bounds__(WM*WN*64, MINW) void gemm_kernel(
    const bf16* __restrict__ A, const float* __restrict__ Af,
    const float* __restrict__ Af2,
    const bf16* __restrict__ Bt, const float* __restrict__ bias,
    int M, int N, int K,
    float* __restrict__ out32, bf16* __restrict__ out16,
    const float* __restrict__ hc, const float* __restrict__ recon,
    float* __restrict__ nloss, float* __restrict__ warg)
{
  constexpr int NT = WM * WN * 64;
  constexpr int FM = (BM / WM) / 16;
  constexpr int FN = (BN / WN) / 16;
  constexpr int RB = BK * 2;                 // bytes per LDS row
  constexpr int KH = BK / 32;                // MFMA K-slices per step
  __shared__ __align__(16) unsigned char smem[(BM + BN) * RB];

  const int tid = threadIdx.x, lane = tid & 63, wid = tid >> 6;
  const int wm = wid / WN, wn = wid % WN;
  const int wm0 = wm * (BM / WM), wn0 = wn * (BN / WN);

  // XCD-chunked bijective remap (hw id%8 = XCD), per z-slice.
  int bx = blockIdx.x, by = blockIdx.y;
  {
    const int gx = gridDim.x;
    const int nwg = gx * gridDim.y;
    if ((nwg & 7) == 0) {
      const int fid = by * gx + bx;
      const int cpx = nwg >> 3;
      const int w = (fid & 7) * cpx + (fid >> 3);
      bx = w % gx; by = w / gx;
    }
  }
  const int i0 = by * BM, j0 = bx * BN;
  const int l15 = lane & 15, lg = lane >> 4;

  f32x4 acc[FM][FN] = {};

  int arow[FM], brow[FN];
#pragma unroll
  for (int mi = 0; mi < FM; ++mi) arow[mi] = wm0 + mi * 16 + l15;
#pragma unroll
  for (int ni = 0; ni < FN; ++ni) brow[ni] = wn0 + ni * 16 + l15;

  auto compute = [&](const unsigned char* cA, const unsigned char* cB) {
#pragma unroll
    for (int kh = 0; kh < KH; ++kh) {
      const int koff = kh * 64 + lg * 16;    // byte offset within RB row
      bf16x8 af[FM], bfr[FN];
#pragma unroll
      for (int mi = 0; mi < FM; ++mi) {
        const int off = (arow[mi] * RB + koff) ^ ((arow[mi] & 7) << 4);
        af[mi] = *reinterpret_cast<const bf16x8*>(cA + off);
      }
#pragma unroll
      for (int ni = 0; ni < FN; ++ni) {
        const int off = (brow[ni] * RB + koff) ^ ((brow[ni] & 7) << 4);
        bfr[ni] = *reinterpret_cast<const bf16x8*>(cB + off);
      }
#pragma unroll
      for (int mi = 0; mi < FM; ++mi)
#pragma unroll
        for (int ni = 0; ni < FN; ++ni)
          acc[mi][ni] = mfma16(af[mi], bfr[ni], acc[mi][ni]);
    }
  };

  // K-window for this block (whole K when KCHUNKS==1).
  const int kcn = K / KCHUNKS;
  const int kb = (KCHUNKS > 1) ? (int)blockIdx.z * kcn : 0;
  for (int kt = kb; kt < kb + kcn; kt += BK) {
    stage_tile<BM, NT, RB>(A, K, i0, kt, smem, tid);
    stage_tile<BN, NT, RB>(Bt, K, j0, kt, smem + BM * RB, tid);
    __syncthreads();
    compute(smem, smem + BM * RB);
    __syncthreads();
  }

  if constexpr (MODE == 5) {
    // Re-layout C through LDS one mi-quarter at a time (32x132 f32 = 16.9 KB)
    // so each thread owns 16 consecutive cols of one row. xn/xc read as f32.
    float* eb = (float*)smem;
#pragma unroll
    for (int mi = 0; mi < FM; ++mi) {
      __syncthreads();
#pragma unroll
      for (int ni = 0; ni < FN; ++ni) {
        const int col = wn0 + ni * 16 + l15;
        const int lr0 = wm * 16 + lg * 4;
#pragma unroll
        for (int r = 0; r < 4; ++r)
          eb[(lr0 + r) * 132 + col] = acc[mi][ni][r];
      }
      __syncthreads();
      const int lrow = tid >> 3;
      const int c0 = (tid & 7) * 16;
      const int grow = i0 + (lrow >> 4) * 64 + mi * 16 + (lrow & 15);
      const int b = grow >> 5;
      const float* xp = Af2  + (size_t)grow * 2048 + j0 + c0;
      const float* cp = Af   + (size_t)b * 2048 + j0 + c0;
      const float* rp = recon + (size_t)b * 2048 + j0 + c0;
      float nl = 0.f, wa = 0.f;
#pragma unroll
      for (int q4 = 0; q4 < 4; ++q4) {
        const float4 xv = *(const float4*)(xp + q4 * 4);
        const float4 cv = *(const float4*)(cp + q4 * 4);
        const float4 rv = *(const float4*)(rp + q4 * 4);
#pragma unroll
        for (int q = 0; q < 4; ++q) {
          const float xf = ((const float*)&xv)[q];
          const float d = xf - ((const float*)&rv)[q] - eb[lrow * 132 + c0 + q4 * 4 + q];
          nl += d * d;
          const float wd = xf - ((const float*)&cv)[q];
          wa += wd * wd;
        }
      }
      nl += __shfl_xor(nl, 1, 64); wa += __shfl_xor(wa, 1, 64);
      nl += __shfl_xor(nl, 2, 64); wa += __shfl_xor(wa, 2, 64);
      nl += __shfl_xor(nl, 4, 64); wa += __shfl_xor(wa, 4, 64);
      if ((tid & 7) == 0) {
        atomicAdd(&nloss[grow], nl);
        atomicAdd(&warg[grow], wa);
      }
    }
  } else {
    // C/D frag: row = (lane>>4)*4 + r, col = lane&15
#pragma unroll
    for (int mi = 0; mi < FM; ++mi) {
#pragma unroll
      for (int ni = 0; ni < FN; ++ni) {
#pragma unroll
        for (int r = 0; r < 4; ++r) {
          const int row = i0 + wm0 + mi * 16 + lg * 4 + r;
          const int col = j0 + wn0 + ni * 16 + l15;
          float v = acc[mi][ni][r];
          if constexpr (MODE == 0) {
            v += bias[col];
            out16[(size_t)row * N + col] = (bf16)fmaxf(v, 0.f);
          } else if constexpr (MODE == 1) {
            v += bias[col];
            out32[(size_t)row * N + col] = v;
          } else if constexpr (MODE == 2) {
            v += bias[col];
            out32[(size_t)row * N + col] = v;
            out16[(size_t)row * N + col] = (bf16)fmaxf(v, 0.f);
          } else if constexpr (MODE == 4) {
            const int b = row >> 5;
            const float m = hc[(size_t)b * 512 + col];
            out16[(size_t)row * N + col] = (bf16)(m > 0.f ? v : 0.f);
          } else if constexpr (MODE == 6) {
            // raw split-K partial: chunk z owns its own buffer slice
            out32[(size_t)blockIdx.z * M * N + (size_t)row * N + col] = v;
          }
        }
      }
    }
  }
}

// ---------------------------------------------------------------------------
// h1 = relu(sum_{c<4} hp[c] + b1) -> bf16.  8 elems/thread.
// 138 MB read + 17 MB write, HBM-bound (~25us).
// ---------------------------------------------------------------------------
__global__ void reduce_h1_kernel(const float* __restrict__ hp,
                                 const float* __restrict__ b1,
                                 bf16* __restrict__ h1) {
  constexpr size_t MN = (size_t)16896 * 512;
  const size_t i = ((size_t)blockIdx.x * 256 + threadIdx.x) * 8;
  const int col = (int)(i & 511);
  float s[8];
  {
    const float4 a0 = *(const float4*)(hp + i);
    const float4 a1 = *(const float4*)(hp + i + 4);
    s[0] = a0.x; s[1] = a0.y; s[2] = a0.z; s[3] = a0.w;
    s[4] = a1.x; s[5] = a1.y; s[6] = a1.z; s[7] = a1.w;
  }
#pragma unroll
  for (int c = 1; c < 4; ++c) {
    const float* p = hp + c * MN + i;
    const float4 a0 = *(const float4*)p;
    const float4 a1 = *(const float4*)(p + 4);
    s[0] += a0.x; s[1] += a0.y; s[2] += a0.z; s[3] += a0.w;
    s[4] += a1.x; s[5] += a1.y; s[6] += a1.z; s[7] += a1.w;
  }
  const float4 b0 = *(const float4*)(b1 + col);
  const float4 b1v = *(const float4*)(b1 + col + 4);
  const float bb[8] = {b0.x, b0.y, b0.z, b0.w, b1v.x, b1v.y, b1v.z, b1v.w};
  bf16x8 v;
#pragma unroll
  for (int q = 0; q < 8; ++q) v[q] = (bf16)fmaxf(s[q] + bb[q], 0.f);
  *(bf16x8*)(h1 + i) = v;
}

// ---------------------------------------------------------------------------
// Cast [x_c; x_nn] f32 -> xb bf16 [16896][2048] (flat contiguous copy).
// ---------------------------------------------------------------------------
__global__ void cast_x_kernel(const float* __restrict__ x_c,
                              const float* __restrict__ x_nn,
                              bf16* __restrict__ xb) {
  const size_t i = ((size_t)blockIdx.x * 256 + threadIdx.x) * 8;
  constexpr size_t XC = (size_t)512 * 2048;
  const float* s = (i < XC) ? x_c + i : x_nn + (i - XC);
  const float4 a = *(const float4*)s;
  const float4 b = *(const float4*)(s + 4);
  bf16x8 v;
  v[0] = (bf16)a.x; v[1] = (bf16)a.y; v[2] = (bf16)a.z; v[3] = (bf16)a.w;
  v[4] = (bf16)b.x; v[5] = (bf16)b.y; v[6] = (bf16)b.z; v[7] = (bf16)b.w;
  *(bf16x8*)(xb + i) = v;
}

// ---------------------------------------------------------------------------
// All four weight transposes in one launch. in [R][C] f32 -> out [C][R] bf16.
// ---------------------------------------------------------------------------
__global__ void transpose_all_kernel(
    const float* __restrict__ W1, const float* __restrict__ W2,
    const float* __restrict__ V1, const float* __restrict__ V2,
    bf16* __restrict__ W1t, bf16* __restrict__ W2t,
    bf16* __restrict__ V1t, bf16* __restrict__ V2t) {
  int blk = blockIdx.x;
  const float* src; bf16* dst; int R, C, gx;
  if (blk < 1024)      { src = W1; dst = W1t; R = 2048; C = 512;  gx = 16; }
  else if (blk < 1056) { blk -= 1024; src = W2; dst = W2t; R = 512; C = 64;   gx = 2;  }
  else if (blk < 1088) { blk -= 1056; src = V1; dst = V1t; R = 64;  C = 512;  gx = 16; }
  else                 { blk -= 1088; src = V2; dst = V2t; R = 512; C = 2048; gx = 64; }
  __shared__ float t[32][33];
  const int c0 = (blk % gx) * 32, r0 = (blk / gx) * 32;
  const int tx = threadIdx.x, ty = threadIdx.y;   // 32 x 8
#pragma unroll
  for (int i = 0; i < 32; i += 8)
    t[ty + i][tx] = src[(size_t)(r0 + ty + i) * C + c0 + tx];
  __syncthreads();
#pragma unroll
  for (int i = 0; i < 32; i += 8)
    dst[(size_t)(c0 + ty + i) * R + r0 + tx] = (bf16)t[tx][ty + i];
}

// dz = z_nn - z_c (bf16), z_c cast to bf16; also zeroes nloss/warg/out.
__global__ void dz_prep_kernel(const float* __restrict__ z,
                               bf16* __restrict__ dzb,
                               bf16* __restrict__ zcb,
                               float* __restrict__ nw,   // nloss..warg, 32768 f32
                               float* __restrict__ out) {
  const int i = blockIdx.x * 256 + threadIdx.x;   // 16896*64 total
  if (i < 32768) nw[i] = 0.f;
  if (i == 0) out[0] = 0.f;
  const int r = i >> 6, j = i & 63;
  const float v = z[i];
  if (r < 512) {
    zcb[i] = (bf16)v;
  } else {
    const int rn = r - 512;
    const int b = rn >> 5;
    dzb[(size_t)rn * 64 + j] = (bf16)(v - z[(size_t)b * 64 + j]);
  }
}

// out = sum_i exp(-warg[i]/4096) * nloss[i] / 16384
__global__ void finalize_kernel(const float* __restrict__ nloss,
                                const float* __restrict__ warg,
                                float* __restrict__ out) {
  const int i = blockIdx.x * 256 + threadIdx.x;   // 16384 total
  float v = expf(-warg[i] * (1.0f / 4096.0f)) * nloss[i] * (1.0f / 16384.0f);
#pragma unroll
  for (int s = 1; s < 64; s <<= 1) v += __shfl_xor(v, s, 64);
  __shared__ float red[4];
  const int lane = threadIdx.x & 63, w = threadIdx.x >> 6;
  if (lane == 0) red[w] = v;
  __syncthreads();
  if (threadIdx.x == 0) atomicAdd(out, red[0] + red[1] + red[2] + red[3]);
}

// ---------------------------------------------------------------------------
extern "C" void kernel_launch(void* const* d_in, const int* in_sizes, int n_in,
                              void* d_out, int out_size, void* d_ws, size_t ws_size,
                              hipStream_t stream) {
  const float* x_c = (const float*)d_in[0];
  const float* x_nn = (const float*)d_in[1];
  const float* W1 = (const float*)d_in[2];
  const float* b1 = (const float*)d_in[3];
  const float* W2 = (const float*)d_in[4];
  const float* b2 = (const float*)d_in[5];
  const float* V1 = (const float*)d_in[6];
  const float* c1 = (const float*)d_in[7];
  const float* V2 = (const float*)d_in[8];
  const float* c2 = (const float*)d_in[9];
  float* out = (float*)d_out;
  char* ws = (char*)d_ws;

  size_t off = 0;
  auto take = [&](size_t n) { size_t o = off; off += n; return o; };
  bf16*  W1t   = (bf16*) (ws + take((size_t)512 * 2048 * 2));
  bf16*  W2t   = (bf16*) (ws + take((size_t)64 * 512 * 2));
  bf16*  V1t   = (bf16*) (ws + take((size_t)512 * 64 * 2));
  bf16*  V2t   = (bf16*) (ws + take((size_t)2048 * 512 * 2));
  bf16*  h1    = (bf16*) (ws + take((size_t)16896 * 512 * 2));
  float* z     = (float*)(ws + take((size_t)16896 * 64 * 4));
  bf16*  dzb   = (bf16*) (ws + take((size_t)16384 * 64 * 2));
  bf16*  zcb   = (bf16*) (ws + take((size_t)512 * 64 * 2));
  float* hc    = (float*)(ws + take((size_t)512 * 512 * 4));
  bf16*  acb   = (bf16*) (ws + take((size_t)512 * 512 * 2));
  float* recon = (float*)(ws + take((size_t)512 * 2048 * 4));
  bf16*  dab   = (bf16*) (ws + take((size_t)16384 * 512 * 2));
  float* nloss = (float*)(ws + take((size_t)16384 * 4));
  float* warg  = (float*)(ws + take((size_t)16384 * 4));
  bf16*  xb    = (bf16*) (ws + take((size_t)16896 * 2048 * 2));
  float* hp    = (float*)(ws + take((size_t)4 * 16896 * 512 * 4));

  // cast x once: [x_c;x_nn] f32 -> xb bf16 (pure BW pass, ~207 MB traffic)
  cast_x_kernel<<<dim3(16896), dim3(256), 0, stream>>>(x_c, x_nn, xb);

  // weight transposes
  transpose_all_kernel<<<dim3(2112), dim3(32, 8), 0, stream>>>(
      W1, W2, V1, V2, W1t, W2t, V1t, V2t);

  // GEMM1 split-K: hp[z] = xb @ W1 over K-window z*512..+512  [16896 x 512]
  // grid (4,132,4) = 2112 blocks x 8 K-steps — GEMM6's exact measured
  // profile (R19: serial chain 32 -> ~8-10 steps).
  gemm_kernel<128, 128, 2, 2, 6, 64, 4><<<dim3(4, 132, 4), dim3(256), 0, stream>>>(
      xb, nullptr, nullptr, W1t, nullptr, 16896, 512, 2048,
      hp, nullptr, nullptr, nullptr, nullptr, nullptr);

  // reduce: h1 = relu(sum hp + b1) bf16
  reduce_h1_kernel<<<dim3(4224), dim3(256), 0, stream>>>(hp, b1, h1);

  // GEMM2: z = h1 @ W2 + b2   [16896 x 64], K=512  (BM=64 -> 264 blocks)
  gemm_kernel<64, 64, 2, 2, 1><<<dim3(1, 264), dim3(256), 0, stream>>>(
      h1, nullptr, nullptr, W2t, b2, 16896, 64, 512,
      z, nullptr, nullptr, nullptr, nullptr, nullptr);

  // dz = z_nn - z_c; cast z_c; zero nloss/warg/out
  dz_prep_kernel<<<dim3(4224), dim3(256), 0, stream>>>(z, dzb, zcb, nloss, out);

  // GEMM3: hc = z_c @ V1 + c1 (f32), acb = relu bf16   [512 x 512], K=64
  gemm_kernel<128, 128, 2, 2, 2><<<dim3(4, 4), dim3(256), 0, stream>>>(
      zcb, nullptr, nullptr, V1t, c1, 512, 512, 64,
      hc, acb, nullptr, nullptr, nullptr, nullptr);

  // GEMM4: recon = acb @ V2 + c2   [512 x 2048], K=512  (BM=64 -> 128 blocks)
  gemm_kernel<64, 128, 2, 2, 1><<<dim3(16, 8), dim3(256), 0, stream>>>(
      acb, nullptr, nullptr, V2t, c2, 512, 2048, 512,
      recon, nullptr, nullptr, nullptr, nullptr, nullptr);

  // GEMM5: dab = (dzb @ V1) * (hc>0)   [16384 x 512], K=64
  gemm_kernel<128, 128, 2, 2, 4><<<dim3(4, 128), dim3(256), 0, stream>>>(
      dzb, nullptr, nullptr, V1t, nullptr, 16384, 512, 64,
      nullptr, dab, hc, nullptr, nullptr, nullptr);

  // GEMM6: Jdz = dab @ V2, fused loss+warg epilogue (f32 x reads)
  gemm_kernel<128, 128, 2, 2, 5><<<dim3(16, 128), dim3(256), 0, stream>>>(
      dab, x_c, x_nn, V2t, nullptr, 16384, 2048, 512,
      nullptr, nullptr, nullptr, recon, nloss, warg);

  finalize_kernel<<<dim3(64), dim3(256), 0, stream>>>(nloss, warg, out);
}

// Round 12
// 163.641 us; speedup vs baseline: 1.4127x; 1.4127x over previous
//
#include <hip/hip_runtime.h>
#include <hip/hip_bf16.h>
#include <cstdint>
#include <cstddef>

// B=512, K=32, D=2048, H=512, Z=64; M_all = 16896; M_nn = 16384
#define DEV __device__ __forceinline__

typedef __bf16 bf16;
typedef __bf16 bf16x8 __attribute__((ext_vector_type(8)));
typedef float f32x4 __attribute__((ext_vector_type(4)));

DEV f32x4 mfma16(bf16x8 a, bf16x8 b, f32x4 c) {
  return __builtin_amdgcn_mfma_f32_16x16x32_bf16(a, b, c, 0, 0, 0);
}

DEV void glds16(const void* g, void* l) {
  __builtin_amdgcn_global_load_lds(
      (const __attribute__((address_space(1))) void*)g,
      (__attribute__((address_space(3))) void*)l, 16, 0, 0);
}

// ---------------------------------------------------------------------------
// Stage ROWSx64 bf16 tile (128B rows) -> LDS, XOR swizzle ((row&7)<<4) via
// pre-swizzled global source column; LDS dest linear (glds requirement).
// ---------------------------------------------------------------------------
template<int ROWS, int NT>
DEV void stage_tile(const bf16* __restrict__ src, int ld, int row0, int k0,
                    unsigned char* lds, int tid) {
  constexpr int CALLS = (ROWS * 128) / (NT * 16);
  const int wid = tid >> 6, lane = tid & 63;
#pragma unroll
  for (int c = 0; c < CALLS; ++c) {
    const int obase = c * (NT * 16) + wid * 1024;   // wave-uniform
    const int o = obase + lane * 16;
    const int row = o >> 7;
    const int scb = (o & 127) ^ ((row & 7) << 4);
    glds16(src + (size_t)(row0 + row) * ld + k0 + (scb >> 1), lds + obase);
  }
}

// ---------------------------------------------------------------------------
// Stage ROWSx64 f32 tile (256B rows) -> LDS, 16B-granular XOR swizzle
// ((row&7)<<4). Source column pre-swizzled; LDS dest linear (glds req).
// ---------------------------------------------------------------------------
template<int ROWS, int NT>
DEV void stage_tile_f32(const float* __restrict__ src, int ld, int row0, int k0,
                        unsigned char* lds, int tid) {
  constexpr int CALLS = (ROWS * 256) / (NT * 16);
  const int wid = tid >> 6, lane = tid & 63;
#pragma unroll
  for (int c = 0; c < CALLS; ++c) {
    const int obase = c * (NT * 16) + wid * 1024;   // wave-uniform
    const int o = obase + lane * 16;
    const int row = o >> 8;
    const int scb = (o & 255) ^ ((row & 7) << 4);
    glds16(src + (size_t)(row0 + row) * ld + k0 + (scb >> 2), lds + obase);
  }
}

// ---------------------------------------------------------------------------
// MFMA GEMM: C[M,N] = A[M,K] @ Bt[N,K]^T, bf16 LDS tiles, f32 accum. BK=64.
// AF32=1 (GEMM1): A is f32 [Af rows<512; Af2 rest], staged RAW via glds;
//   fragment load reads two f32x4 + casts to bf16 in-register. x is read
//   exactly once from HBM — no separate cast pass (the cast pass never paid:
//   ~30us HBM round-trip, R5/R8-R11 all >= 173.7 vs R4's 168.6).
// R20 model (bench totals only; rocprof/total decompositions disagree +-15us):
//   GEMM1 cost ~ staged-bytes x tile-intensity. R4 (AF32 BM=64): 1.08 GB at
//   43.7 FLOP/B -> 118us. 128^2 tile = 65.5 FLOP/B and the bf16 instance
//   measured <75us at 554 MB (fill-kernel floor argument). This round: AF32
//   at 128^2 — 675 MB staged (-37% vs R4), 48KB LDS (3 blocks/CU), x once.
// MODE: 0 relu->bf16; 1 f32+bias; 2 both; 4 mask by hc>0 -> bf16;
//       5 fused loss (nloss/warg via LDS C re-layout, f32 x reads).
// ---------------------------------------------------------------------------
template<int BM, int BN, int WM, int WN, int MODE, int AF32, int MINW = 2>
__global__ __launch_bounds__(WM*WN*64, MINW) void gemm_kernel(
    const bf16* __restrict__ A, const float* __restrict__ Af,
    const float* __restrict__ Af2,
    const bf16* __restrict__ Bt, const float* __restrict__ bias,
    int M, int N, int K,
    float* __restrict__ out32, bf16* __restrict__ out16,
    const float* __restrict__ hc, const float* __restrict__ recon,
    float* __restrict__ nloss, float* __restrict__ warg)
{
  constexpr int NT = WM * WN * 64;
  constexpr int FM = (BM / WM) / 16;
  constexpr int FN = (BN / WN) / 16;
  __shared__ __align__(16) unsigned char smem[AF32 ? (BM * 256 + BN * 128)
                                                   : (BM + BN) * 128];

  const int tid = threadIdx.x, lane = tid & 63, wid = tid >> 6;
  const int wm = wid / WN, wn = wid % WN;
  const int wm0 = wm * (BM / WM), wn0 = wn * (BN / WN);

  // XCD-chunked bijective remap (hw id%8 = XCD).
  int bx = blockIdx.x, by = blockIdx.y;
  {
    const int gx = gridDim.x;
    const int nwg = gx * gridDim.y;
    if ((nwg & 7) == 0) {
      const int fid = by * gx + bx;
      const int cpx = nwg >> 3;
      const int w = (fid & 7) * cpx + (fid >> 3);
      bx = w % gx; by = w / gx;
    }
  }
  const int i0 = by * BM, j0 = bx * BN;
  const int l15 = lane & 15, lg = lane >> 4;

  f32x4 acc[FM][FN] = {};

  int arow[FM], brow[FN];
#pragma unroll
  for (int mi = 0; mi < FM; ++mi) arow[mi] = wm0 + mi * 16 + l15;
#pragma unroll
  for (int ni = 0; ni < FN; ++ni) brow[ni] = wn0 + ni * 16 + l15;

  auto compute = [&](const unsigned char* cA, const unsigned char* cB) {
#pragma unroll
    for (int kh = 0; kh < 2; ++kh) {
      bf16x8 af[FM], bfr[FN];
      if constexpr (AF32) {
        const int Fb = kh * 128 + lg * 32;   // f32 row: 256B, elems [kh*32+lg*8, +8)
#pragma unroll
        for (int mi = 0; mi < FM; ++mi) {
          const int r = arow[mi];
          const unsigned char* p = cA + r * 256;
          const f32x4 lo = *reinterpret_cast<const f32x4*>(p + ((Fb)      ^ ((r & 7) << 4)));
          const f32x4 hi = *reinterpret_cast<const f32x4*>(p + ((Fb + 16) ^ ((r & 7) << 4)));
          bf16x8 a;
          a[0] = (bf16)lo[0]; a[1] = (bf16)lo[1]; a[2] = (bf16)lo[2]; a[3] = (bf16)lo[3];
          a[4] = (bf16)hi[0]; a[5] = (bf16)hi[1]; a[6] = (bf16)hi[2]; a[7] = (bf16)hi[3];
          af[mi] = a;
        }
      } else {
        const int koff = kh * 64 + lg * 16;
#pragma unroll
        for (int mi = 0; mi < FM; ++mi) {
          const int off = (arow[mi] * 128 + koff) ^ ((arow[mi] & 7) << 4);
          af[mi] = *reinterpret_cast<const bf16x8*>(cA + off);
        }
      }
      const int koffB = kh * 64 + lg * 16;
#pragma unroll
      for (int ni = 0; ni < FN; ++ni) {
        const int off = (brow[ni] * 128 + koffB) ^ ((brow[ni] & 7) << 4);
        bfr[ni] = *reinterpret_cast<const bf16x8*>(cB + off);
      }
#pragma unroll
      for (int mi = 0; mi < FM; ++mi)
#pragma unroll
        for (int ni = 0; ni < FN; ++ni)
          acc[mi][ni] = mfma16(af[mi], bfr[ni], acc[mi][ni]);
    }
  };

  if constexpr (AF32) {
    const float* As = (i0 < 512) ? Af + (size_t)i0 * K
                                 : Af2 + (size_t)(i0 - 512) * K;
    for (int kt = 0; kt < K; kt += 64) {
      stage_tile_f32<BM, NT>(As, K, 0, kt, smem, tid);
      stage_tile<BN, NT>(Bt, K, j0, kt, smem + BM * 256, tid);
      __syncthreads();
      compute(smem, smem + BM * 256);
      __syncthreads();
    }
  } else {
    for (int kt = 0; kt < K; kt += 64) {
      stage_tile<BM, NT>(A, K, i0, kt, smem, tid);
      stage_tile<BN, NT>(Bt, K, j0, kt, smem + BM * 128, tid);
      __syncthreads();
      compute(smem, smem + BM * 128);
      __syncthreads();
    }
  }

  if constexpr (MODE == 5) {
    // Re-layout C through LDS one mi-quarter at a time (32x132 f32 = 16.9 KB)
    // so each thread owns 16 consecutive cols of one row. xn/xc read as f32.
    float* eb = (float*)smem;
#pragma unroll
    for (int mi = 0; mi < FM; ++mi) {
      __syncthreads();
#pragma unroll
      for (int ni = 0; ni < FN; ++ni) {
        const int col = wn0 + ni * 16 + l15;
        const int lr0 = wm * 16 + lg * 4;
#pragma unroll
        for (int r = 0; r < 4; ++r)
          eb[(lr0 + r) * 132 + col] = acc[mi][ni][r];
      }
      __syncthreads();
      const int lrow = tid >> 3;
      const int c0 = (tid & 7) * 16;
      const int grow = i0 + (lrow >> 4) * 64 + mi * 16 + (lrow & 15);
      const int b = grow >> 5;
      const float* xp = Af2  + (size_t)grow * 2048 + j0 + c0;
      const float* cp = Af   + (size_t)b * 2048 + j0 + c0;
      const float* rp = recon + (size_t)b * 2048 + j0 + c0;
      float nl = 0.f, wa = 0.f;
#pragma unroll
      for (int q4 = 0; q4 < 4; ++q4) {
        const float4 xv = *(const float4*)(xp + q4 * 4);
        const float4 cv = *(const float4*)(cp + q4 * 4);
        const float4 rv = *(const float4*)(rp + q4 * 4);
#pragma unroll
        for (int q = 0; q < 4; ++q) {
          const float xf = ((const float*)&xv)[q];
          const float d = xf - ((const float*)&rv)[q] - eb[lrow * 132 + c0 + q4 * 4 + q];
          nl += d * d;
          const float wd = xf - ((const float*)&cv)[q];
          wa += wd * wd;
        }
      }
      nl += __shfl_xor(nl, 1, 64); wa += __shfl_xor(wa, 1, 64);
      nl += __shfl_xor(nl, 2, 64); wa += __shfl_xor(wa, 2, 64);
      nl += __shfl_xor(nl, 4, 64); wa += __shfl_xor(wa, 4, 64);
      if ((tid & 7) == 0) {
        atomicAdd(&nloss[grow], nl);
        atomicAdd(&warg[grow], wa);
      }
    }
  } else {
    // C/D frag: row = (lane>>4)*4 + r, col = lane&15
#pragma unroll
    for (int mi = 0; mi < FM; ++mi) {
#pragma unroll
      for (int ni = 0; ni < FN; ++ni) {
#pragma unroll
        for (int r = 0; r < 4; ++r) {
          const int row = i0 + wm0 + mi * 16 + lg * 4 + r;
          const int col = j0 + wn0 + ni * 16 + l15;
          float v = acc[mi][ni][r];
          if constexpr (MODE == 0) {
            v += bias[col];
            out16[(size_t)row * N + col] = (bf16)fmaxf(v, 0.f);
          } else if constexpr (MODE == 1) {
            v += bias[col];
            out32[(size_t)row * N + col] = v;
          } else if constexpr (MODE == 2) {
            v += bias[col];
            out32[(size_t)row * N + col] = v;
            out16[(size_t)row * N + col] = (bf16)fmaxf(v, 0.f);
          } else if constexpr (MODE == 4) {
            const int b = row >> 5;
            const float m = hc[(size_t)b * 512 + col];
            out16[(size_t)row * N + col] = (bf16)(m > 0.f ? v : 0.f);
          }
        }
      }
    }
  }
}

// ---------------------------------------------------------------------------
// All four weight transposes in one launch. in [R][C] f32 -> out [C][R] bf16.
// ---------------------------------------------------------------------------
__global__ void transpose_all_kernel(
    const float* __restrict__ W1, const float* __restrict__ W2,
    const float* __restrict__ V1, const float* __restrict__ V2,
    bf16* __restrict__ W1t, bf16* __restrict__ W2t,
    bf16* __restrict__ V1t, bf16* __restrict__ V2t) {
  int blk = blockIdx.x;
  const float* src; bf16* dst; int R, C, gx;
  if (blk < 1024)      { src = W1; dst = W1t; R = 2048; C = 512;  gx = 16; }
  else if (blk < 1056) { blk -= 1024; src = W2; dst = W2t; R = 512; C = 64;   gx = 2;  }
  else if (blk < 1088) { blk -= 1056; src = V1; dst = V1t; R = 64;  C = 512;  gx = 16; }
  else                 { blk -= 1088; src = V2; dst = V2t; R = 512; C = 2048; gx = 64; }
  __shared__ float t[32][33];
  const int c0 = (blk % gx) * 32, r0 = (blk / gx) * 32;
  const int tx = threadIdx.x, ty = threadIdx.y;   // 32 x 8
#pragma unroll
  for (int i = 0; i < 32; i += 8)
    t[ty + i][tx] = src[(size_t)(r0 + ty + i) * C + c0 + tx];
  __syncthreads();
#pragma unroll
  for (int i = 0; i < 32; i += 8)
    dst[(size_t)(c0 + ty + i) * R + r0 + tx] = (bf16)t[tx][ty + i];
}

// dz = z_nn - z_c (bf16), z_c cast to bf16; also zeroes nloss/warg/out.
__global__ void dz_prep_kernel(const float* __restrict__ z,
                               bf16* __restrict__ dzb,
                               bf16* __restrict__ zcb,
                               float* __restrict__ nw,   // nloss..warg, 32768 f32
                               float* __restrict__ out) {
  const int i = blockIdx.x * 256 + threadIdx.x;   // 16896*64 total
  if (i < 32768) nw[i] = 0.f;
  if (i == 0) out[0] = 0.f;
  const int r = i >> 6, j = i & 63;
  const float v = z[i];
  if (r < 512) {
    zcb[i] = (bf16)v;
  } else {
    const int rn = r - 512;
    const int b = rn >> 5;
    dzb[(size_t)rn * 64 + j] = (bf16)(v - z[(size_t)b * 64 + j]);
  }
}

// out = sum_i exp(-warg[i]/4096) * nloss[i] / 16384
__global__ void finalize_kernel(const float* __restrict__ nloss,
                                const float* __restrict__ warg,
                                float* __restrict__ out) {
  const int i = blockIdx.x * 256 + threadIdx.x;   // 16384 total
  float v = expf(-warg[i] * (1.0f / 4096.0f)) * nloss[i] * (1.0f / 16384.0f);
#pragma unroll
  for (int s = 1; s < 64; s <<= 1) v += __shfl_xor(v, s, 64);
  __shared__ float red[4];
  const int lane = threadIdx.x & 63, w = threadIdx.x >> 6;
  if (lane == 0) red[w] = v;
  __syncthreads();
  if (threadIdx.x == 0) atomicAdd(out, red[0] + red[1] + red[2] + red[3]);
}

// ---------------------------------------------------------------------------
extern "C" void kernel_launch(void* const* d_in, const int* in_sizes, int n_in,
                              void* d_out, int out_size, void* d_ws, size_t ws_size,
                              hipStream_t stream) {
  const float* x_c = (const float*)d_in[0];
  const float* x_nn = (const float*)d_in[1];
  const float* W1 = (const float*)d_in[2];
  const float* b1 = (const float*)d_in[3];
  const float* W2 = (const float*)d_in[4];
  const float* b2 = (const float*)d_in[5];
  const float* V1 = (const float*)d_in[6];
  const float* c1 = (const float*)d_in[7];
  const float* V2 = (const float*)d_in[8];
  const float* c2 = (const float*)d_in[9];
  float* out = (float*)d_out;
  char* ws = (char*)d_ws;

  size_t off = 0;
  auto take = [&](size_t n) { size_t o = off; off += n; return o; };
  bf16*  W1t   = (bf16*) (ws + take((size_t)512 * 2048 * 2));
  bf16*  W2t   = (bf16*) (ws + take((size_t)64 * 512 * 2));
  bf16*  V1t   = (bf16*) (ws + take((size_t)512 * 64 * 2));
  bf16*  V2t   = (bf16*) (ws + take((size_t)2048 * 512 * 2));
  bf16*  h1    = (bf16*) (ws + take((size_t)16896 * 512 * 2));
  float* z     = (float*)(ws + take((size_t)16896 * 64 * 4));
  bf16*  dzb   = (bf16*) (ws + take((size_t)16384 * 64 * 2));
  bf16*  zcb   = (bf16*) (ws + take((size_t)512 * 64 * 2));
  float* hc    = (float*)(ws + take((size_t)512 * 512 * 4));
  bf16*  acb   = (bf16*) (ws + take((size_t)512 * 512 * 2));
  float* recon = (float*)(ws + take((size_t)512 * 2048 * 4));
  bf16*  dab   = (bf16*) (ws + take((size_t)16384 * 512 * 2));
  float* nloss = (float*)(ws + take((size_t)16384 * 4));
  float* warg  = (float*)(ws + take((size_t)16384 * 4));

  // weight transposes
  transpose_all_kernel<<<dim3(2112), dim3(32, 8), 0, stream>>>(
      W1, W2, V1, V2, W1t, W2t, V1t, V2t);

  // GEMM1: h1 = relu([xc;xnn]_f32 @ W1 + b1)  [16896 x 512], K=2048
  // AF32 128x128 tile: x read ONCE as f32 (no cast pass), staged 675 MB
  // (-37% vs R4's BM=64), 65.5 FLOP/staged-byte, 48KB LDS -> 3 blocks/CU,
  // grid (4,132)=528, MINW=1 (acc=64 VGPR + frags needs headroom).
  gemm_kernel<128, 128, 2, 2, 0, 1, 1><<<dim3(4, 132), dim3(256), 0, stream>>>(
      nullptr, x_c, x_nn, W1t, b1, 16896, 512, 2048,
      nullptr, h1, nullptr, nullptr, nullptr, nullptr);

  // GEMM2: z = h1 @ W2 + b2   [16896 x 64], K=512  (BM=64 -> 264 blocks)
  gemm_kernel<64, 64, 2, 2, 1, 0><<<dim3(1, 264), dim3(256), 0, stream>>>(
      h1, nullptr, nullptr, W2t, b2, 16896, 64, 512,
      z, nullptr, nullptr, nullptr, nullptr, nullptr);

  // dz = z_nn - z_c; cast z_c; zero nloss/warg/out
  dz_prep_kernel<<<dim3(4224), dim3(256), 0, stream>>>(z, dzb, zcb, nloss, out);

  // GEMM3: hc = z_c @ V1 + c1 (f32), acb = relu bf16   [512 x 512], K=64
  gemm_kernel<128, 128, 2, 2, 2, 0><<<dim3(4, 4), dim3(256), 0, stream>>>(
      zcb, nullptr, nullptr, V1t, c1, 512, 512, 64,
      hc, acb, nullptr, nullptr, nullptr, nullptr);

  // GEMM4: recon = acb @ V2 + c2   [512 x 2048], K=512  (BM=64 -> 128 blocks)
  gemm_kernel<64, 128, 2, 2, 1, 0><<<dim3(16, 8), dim3(256), 0, stream>>>(
      acb, nullptr, nullptr, V2t, c2, 512, 2048, 512,
      recon, nullptr, nullptr, nullptr, nullptr, nullptr);

  // GEMM5: dab = (dzb @ V1) * (hc>0)   [16384 x 512], K=64
  gemm_kernel<128, 128, 2, 2, 4, 0><<<dim3(4, 128), dim3(256), 0, stream>>>(
      dzb, nullptr, nullptr, V1t, nullptr, 16384, 512, 64,
      nullptr, dab, hc, nullptr, nullptr, nullptr);

  // GEMM6: Jdz = dab @ V2, fused loss+warg epilogue (f32 x reads)
  gemm_kernel<128, 128, 2, 2, 5, 0><<<dim3(16, 128), dim3(256), 0, stream>>>(
      dab, x_c, x_nn, V2t, nullptr, 16384, 2048, 512,
      nullptr, nullptr, nullptr, recon, nloss, warg);

  finalize_kernel<<<dim3(64), dim3(256), 0, stream>>>(nloss, warg, out);
}